// Round 7
// baseline (549.309 us; speedup 1.0000x reference)
//
#include <hip/hip_runtime.h>
#include <hip/hip_bf16.h>

// 3-layer GCN: bf16-MFMA GEMMs + CSR gather-reduce aggregation.
//   hs = bf16( dinv[row] * (act(A) @ W) )     (MFMA GEMM, act = BN+ReLU fused)
//   y[i] = dinv[i]*(hs[i] + sum_{e: s->i} hs[s]) + b  (fp32 acc, bf16 out)
// Aggregate history: time tracks row-gather chain count, not bytes
// (r5 bf16 no-op) nor write size (r6 no-op); r4 (1024 blk + x4 unroll)
// regressed. This round: 16 lanes x 16B (uint4) per row -> 4 chains/wave
// (was 2), half the gather instructions; 512 blocks, x2 unroll kept.

typedef __attribute__((ext_vector_type(8))) short short8;   // 8 bf16
typedef __attribute__((ext_vector_type(4))) float f32x4;    // 4 fp32 acc

__device__ inline unsigned short f2bf(float f) {  // round-to-nearest-even
    unsigned int u = __float_as_uint(f);
    return (unsigned short)((u + 0x7fff + ((u >> 16) & 1)) >> 16);
}
__device__ inline float bf2f_lo(unsigned int p) { return __uint_as_float(p << 16); }
__device__ inline float bf2f_hi(unsigned int p) { return __uint_as_float(p & 0xffff0000u); }

__device__ inline void bf8_acc(uint4 v, float* a) {
    a[0] += bf2f_lo(v.x); a[1] += bf2f_hi(v.x);
    a[2] += bf2f_lo(v.y); a[3] += bf2f_hi(v.y);
    a[4] += bf2f_lo(v.z); a[5] += bf2f_hi(v.z);
    a[6] += bf2f_lo(v.w); a[7] += bf2f_hi(v.w);
}

__global__ void count_deg_kernel(const int* __restrict__ dst, int E,
                                 int* __restrict__ rowptr1) {
    int e = blockIdx.x * blockDim.x + threadIdx.x;
    if (e < E) atomicAdd(rowptr1 + dst[e], 1);
}

__global__ void dinv_kernel(const int* __restrict__ rowptr, int n,
                            float* __restrict__ dinv) {
    int i = blockIdx.x * blockDim.x + threadIdx.x;
    if (i < n) dinv[i] = rsqrtf((float)(rowptr[i + 1] + 1));
}

// ---- 3-phase parallel inclusive scan over rowptr[0..total) ----
__global__ __launch_bounds__(256) void scanA_kernel(int* __restrict__ data,
                                                    int total,
                                                    int* __restrict__ bsum) {
    __shared__ int sh[256];
    const int t = threadIdx.x;
    const int base = blockIdx.x * 2048 + t * 8;
    int v[8];
    int run = 0;
#pragma unroll
    for (int j = 0; j < 8; ++j) {
        int idx = base + j;
        int x = (idx < total) ? data[idx] : 0;
        run += x;
        v[j] = run;
    }
    sh[t] = run;
    __syncthreads();
#pragma unroll
    for (int off = 1; off < 256; off <<= 1) {
        int add = (t >= off) ? sh[t - off] : 0;
        __syncthreads();
        sh[t] += add;
        __syncthreads();
    }
    int prev = (t > 0) ? sh[t - 1] : 0;
#pragma unroll
    for (int j = 0; j < 8; ++j) {
        int idx = base + j;
        if (idx < total) data[idx] = v[j] + prev;
    }
    if (t == 255) bsum[blockIdx.x] = sh[255];
}

__global__ void scanB_kernel(int* __restrict__ bsum, int nb) {
    __shared__ int sh[64];
    const int t = threadIdx.x;
    sh[t] = (t < nb) ? bsum[t] : 0;
    __syncthreads();
#pragma unroll
    for (int off = 1; off < 64; off <<= 1) {
        int add = (t >= off) ? sh[t - off] : 0;
        __syncthreads();
        sh[t] += add;
        __syncthreads();
    }
    if (t < nb) bsum[t] = sh[t];
}

__global__ __launch_bounds__(256) void scanC_kernel(int* __restrict__ data,
                                                    int total,
                                                    const int* __restrict__ bsum) {
    if (blockIdx.x == 0) return;
    const int off = bsum[blockIdx.x - 1];
    const int base = blockIdx.x * 2048 + threadIdx.x * 8;
#pragma unroll
    for (int j = 0; j < 8; ++j) {
        int idx = base + j;
        if (idx < total) data[idx] += off;
    }
}

__global__ void csr_build_kernel(const int* __restrict__ src,
                                 const int* __restrict__ dst, int E,
                                 int* __restrict__ rowptr,
                                 int* __restrict__ csr_src) {
    int e = blockIdx.x * blockDim.x + threadIdx.x;
    if (e < E) {
        int pos = atomicAdd(rowptr + dst[e], 1);
        csr_src[pos] = src[e];
    }
}

// Wt[nn][k] = bf16(W[k][nn]); K=128 fixed
__global__ void wt_bf16_kernel(const float* __restrict__ W, int NC,
                               unsigned short* __restrict__ Wt) {
    int idx = blockIdx.x * blockDim.x + threadIdx.x;
    if (idx < 128 * NC) {
        int k = idx / NC, nn = idx % NC;
        Wt[nn * 128 + k] = f2bf(W[idx]);
    }
}

// x fp32 -> bf16 (4 elems/thread)
__global__ void xcvt_kernel(const float* __restrict__ x,
                            unsigned short* __restrict__ xb, int total4) {
    int i = blockIdx.x * blockDim.x + threadIdx.x;
    if (i < total4) {
        float4 v = reinterpret_cast<const float4*>(x)[i];
        uint2 p;
        p.x = f2bf(v.x) | ((unsigned)f2bf(v.y) << 16);
        p.y = f2bf(v.z) | ((unsigned)f2bf(v.w) << 16);
        reinterpret_cast<uint2*>(xb)[i] = p;
    }
}

// C[n x NC] = bf16( dinv[row] * (act(A[n x 128]) @ W) ), A bf16, Wt bf16 (NCx128).
// act = identity or BN(scale,shift)+ReLU applied during A-staging.
// MFMA 16x16x32 bf16; layouts per m89/m120-verified mappings.
template <int NC, bool BN>
__global__ __launch_bounds__(256) void gemm_mfma(
    const unsigned short* __restrict__ A, const unsigned short* __restrict__ Wt,
    unsigned short* __restrict__ C, int n, const float* __restrict__ ss,
    const float* __restrict__ dinv) {
    __shared__ unsigned short Asd[64][136];   // +8 pad: 2-way bank (free)
    __shared__ unsigned short Bsd[NC][136];
    const int tid = threadIdx.x;
    const int wave = tid >> 6;
    const int lane = tid & 63;
    const int row0 = blockIdx.x * 64;

    // stage Bt (NC x 128)
    for (int idx = tid; idx < NC * 16; idx += 256) {
        int r = idx >> 4;
        int c = (idx & 15) * 8;
        uint4 v = *reinterpret_cast<const uint4*>(Wt + r * 128 + c);
        *reinterpret_cast<uint4*>(&Bsd[r][c]) = v;
    }
    // stage A rows (64 x 128) with optional BN+ReLU
    for (int idx = tid; idx < 64 * 16; idx += 256) {
        int r = idx >> 4;
        int c = (idx & 15) * 8;
        int grow = row0 + r;
        uint4 v = make_uint4(0u, 0u, 0u, 0u);
        if (grow < n)
            v = *reinterpret_cast<const uint4*>(A + (size_t)grow * 128 + c);
        if (BN) {
            unsigned int p[4] = {v.x, v.y, v.z, v.w};
#pragma unroll
            for (int h = 0; h < 4; ++h) {
                int f = c + h * 2;
                float lo = fmaxf(fmaf(bf2f_lo(p[h]), ss[f], ss[128 + f]), 0.f);
                float hi = fmaxf(fmaf(bf2f_hi(p[h]), ss[f + 1], ss[129 + f]), 0.f);
                p[h] = f2bf(lo) | ((unsigned)f2bf(hi) << 16);
            }
            v = make_uint4(p[0], p[1], p[2], p[3]);
        }
        *reinterpret_cast<uint4*>(&Asd[r][c]) = v;
    }
    __syncthreads();

    f32x4 acc[NC / 16];
#pragma unroll
    for (int t = 0; t < NC / 16; ++t) acc[t] = (f32x4)(0.f);

    const int l15 = lane & 15;
    const int quad = lane >> 4;
#pragma unroll
    for (int kb = 0; kb < 128; kb += 32) {
        short8 a = *reinterpret_cast<const short8*>(&Asd[wave * 16 + l15][kb + quad * 8]);
#pragma unroll
        for (int t = 0; t < NC / 16; ++t) {
            short8 b = *reinterpret_cast<const short8*>(&Bsd[t * 16 + l15][kb + quad * 8]);
            acc[t] = __builtin_amdgcn_mfma_f32_16x16x32_bf16(a, b, acc[t], 0, 0, 0);
        }
    }

    // epilogue: row = row0 + wave*16 + quad*4 + r ; col = t*16 + (lane&15)
    const int rbase = row0 + wave * 16 + quad * 4;
    float dv[4] = {0.f, 0.f, 0.f, 0.f};
    if (rbase < n) {  // dinv padded by +64 in ws
        float4 d4 = *reinterpret_cast<const float4*>(dinv + rbase);
        dv[0] = d4.x; dv[1] = d4.y; dv[2] = d4.z; dv[3] = d4.w;
    }
#pragma unroll
    for (int t = 0; t < NC / 16; ++t) {
        int col = t * 16 + l15;
#pragma unroll
        for (int r = 0; r < 4; ++r) {
            int row = rbase + r;
            if (row < n)
                C[(size_t)row * NC + col] = f2bf(acc[t][r] * dv[r]);
        }
    }
}

// y[i] = dinv[i]*(hs[i] + sum_{e in row i} hs[csr_src[e]]) + bias
// hs bf16; 16B (8 bf16) per lane -> F/8 lanes per row, 4 chains/wave @F=128.
// fp32 accumulate; out bf16 (OBF) or fp32. Optional BN stats (F=128 shape).
// rowptr is POST-BUILD (rowptr[i] = end of row i; start = rowptr[i-1]).
template <int F, bool STATS, bool OBF>
__global__ __launch_bounds__(256) void aggregate_kernel(
    const unsigned short* __restrict__ hs, const int* __restrict__ csr_src,
    const int* __restrict__ rowptr, const float* __restrict__ dinv,
    const float* __restrict__ bias, void* __restrict__ outp, int n,
    float* __restrict__ stats) {
    const int LANES = F / 8;            // 16 for F=128, 8 for F=64
    const int GROUPS = 256 / LANES;
    const int lane = threadIdx.x % LANES;
    const int grp = threadIdx.x / LANES;
    const int fq = lane * 8;
    float bb[8];
#pragma unroll
    for (int j = 0; j < 8; ++j) bb[j] = bias[fq + j];
    float s[8] = {}, sq[8] = {};

    for (int i = blockIdx.x * GROUPS + grp; i < n; i += gridDim.x * GROUPS) {
        int beg = (i == 0) ? 0 : rowptr[i - 1];
        int end = rowptr[i];
        float a[8] = {};
        bf8_acc(*reinterpret_cast<const uint4*>(hs + (size_t)i * F + fq), a);
        int e = beg;
        for (; e + 1 < end; e += 2) {
            int s0 = csr_src[e], s1 = csr_src[e + 1];
            uint4 v0 = *reinterpret_cast<const uint4*>(hs + (size_t)s0 * F + fq);
            uint4 v1 = *reinterpret_cast<const uint4*>(hs + (size_t)s1 * F + fq);
            bf8_acc(v0, a);
            bf8_acc(v1, a);
        }
        if (e < end) {
            int s0 = csr_src[e];
            bf8_acc(*reinterpret_cast<const uint4*>(hs + (size_t)s0 * F + fq), a);
        }
        float di = dinv[i];
        float y[8];
#pragma unroll
        for (int j = 0; j < 8; ++j) y[j] = fmaf(di, a[j], bb[j]);
        if (OBF) {
            uint4 pk;
            pk.x = f2bf(y[0]) | ((unsigned)f2bf(y[1]) << 16);
            pk.y = f2bf(y[2]) | ((unsigned)f2bf(y[3]) << 16);
            pk.z = f2bf(y[4]) | ((unsigned)f2bf(y[5]) << 16);
            pk.w = f2bf(y[6]) | ((unsigned)f2bf(y[7]) << 16);
            *reinterpret_cast<uint4*>((unsigned short*)outp + (size_t)i * F + fq) = pk;
        } else {
            float* op = (float*)outp + (size_t)i * F + fq;
            *reinterpret_cast<float4*>(op) = make_float4(y[0], y[1], y[2], y[3]);
            *reinterpret_cast<float4*>(op + 4) = make_float4(y[4], y[5], y[6], y[7]);
        }
        if (STATS) {
#pragma unroll
            for (int j = 0; j < 8; ++j) {
                s[j] += y[j];
                sq[j] = fmaf(y[j], y[j], sq[j]);
            }
        }
    }
    if (STATS) {  // F=128 shape: LANES=16, GROUPS=16
        __shared__ float sred[16][17];
#pragma unroll
        for (int j = 0; j < 16; ++j) {
            float v = (j < 8) ? s[j] : sq[j - 8];
            sred[lane][grp] = v;
            __syncthreads();
            if (grp == 0) {
                float t = 0.f;
#pragma unroll
                for (int g = 0; g < 16; ++g) t += sred[lane][g];
                int f = fq + (j & 7);
                atomicAdd(stats + ((j < 8) ? f : 128 + f), t);
            }
            __syncthreads();
        }
    }
}

// scale = g * rsqrt(var+eps); shift = be - mean*scale
__global__ void finalize_kernel(const float* __restrict__ stats,
                                const float* __restrict__ g,
                                const float* __restrict__ be, float invn,
                                float* __restrict__ ss) {
    int f = threadIdx.x;
    float mean = stats[f] * invn;
    float var = fmaf(-mean, mean, stats[128 + f] * invn);
    float sc = g[f] * rsqrtf(var + 1e-5f);
    ss[f] = sc;
    ss[128 + f] = fmaf(-mean, sc, be[f]);
}

extern "C" void kernel_launch(void* const* d_in, const int* in_sizes, int n_in,
                              void* d_out, int out_size, void* d_ws,
                              size_t ws_size, hipStream_t stream) {
    const float* x   = (const float*)d_in[0];
    const int*   ei  = (const int*)d_in[1];
    const float* W1  = (const float*)d_in[2];
    const float* b1  = (const float*)d_in[3];
    const float* g1  = (const float*)d_in[4];
    const float* be1 = (const float*)d_in[5];
    const float* W2  = (const float*)d_in[6];
    const float* b2  = (const float*)d_in[7];
    const float* g2  = (const float*)d_in[8];
    const float* be2 = (const float*)d_in[9];
    const float* W3  = (const float*)d_in[10];
    const float* b3  = (const float*)d_in[11];
    float* out = (float*)d_out;

    const int n = in_sizes[0] / 128;
    const int E = in_sizes[1] / 2;
    const int* src = ei;
    const int* dst = ei + E;

    float* wsf    = (float*)d_ws;
    float* dinv   = wsf;                         // n + 64 floats (padded)
    float* stats  = dinv + n + 64;               // 256
    float* ss     = stats + 256;                 // 256
    int*   rowptr = (int*)(ss + 256);            // n+1 ints
    int*   bsum   = rowptr + (n + 1);            // 64 ints
    int*   csrsrc = bsum + 64;                   // E ints
    unsigned short* wt1 = (unsigned short*)(csrsrc + E);      // 128*128
    unsigned short* wt2 = wt1 + 128 * 128;                    // 128*128
    unsigned short* wt3 = wt2 + 128 * 128;                    // 64*128
    unsigned short* abuf = wt3 + 64 * 128;                    // n*128 bf16
    unsigned short* hsb  = abuf + (size_t)n * 128;            // n*128 bf16

    const int total = n + 1;
    const int nb = (total + 2047) / 2048;

    // ---- CSR build + dinv + weight/x conversion ----
    hipMemsetAsync(rowptr, 0, (size_t)total * 4, stream);
    count_deg_kernel<<<(E + 255) / 256, 256, 0, stream>>>(dst, E, rowptr + 1);
    dinv_kernel<<<(n + 255) / 256, 256, 0, stream>>>(rowptr, n, dinv);
    scanA_kernel<<<nb, 256, 0, stream>>>(rowptr, total, bsum);
    scanB_kernel<<<1, 64, 0, stream>>>(bsum, nb);
    scanC_kernel<<<nb, 256, 0, stream>>>(rowptr, total, bsum);
    csr_build_kernel<<<(E + 255) / 256, 256, 0, stream>>>(src, dst, E, rowptr, csrsrc);
    wt_bf16_kernel<<<(128 * 128 + 255) / 256, 256, 0, stream>>>(W1, 128, wt1);
    wt_bf16_kernel<<<(128 * 128 + 255) / 256, 256, 0, stream>>>(W2, 128, wt2);
    wt_bf16_kernel<<<(128 * 64 + 255) / 256, 256, 0, stream>>>(W3, 64, wt3);
    xcvt_kernel<<<((n * 32) + 255) / 256, 256, 0, stream>>>(x, abuf, n * 32);

    const int gemmGrid = (n + 63) / 64;
    const int aggGrid = 512;  // proven best block count (r3/r4)

    // ---- layer 1 ----
    gemm_mfma<128, false><<<gemmGrid, 256, 0, stream>>>(abuf, wt1, hsb, n, nullptr, dinv);
    hipMemsetAsync(stats, 0, 256 * 4, stream);
    aggregate_kernel<128, true, true><<<aggGrid, 256, 0, stream>>>(hsb, csrsrc, rowptr, dinv, b1, abuf, n, stats);
    finalize_kernel<<<1, 128, 0, stream>>>(stats, g1, be1, 1.0f / n, ss);

    // ---- layer 2 ----
    gemm_mfma<128, true><<<gemmGrid, 256, 0, stream>>>(abuf, wt2, hsb, n, ss, dinv);
    hipMemsetAsync(stats, 0, 256 * 4, stream);
    aggregate_kernel<128, true, true><<<aggGrid, 256, 0, stream>>>(hsb, csrsrc, rowptr, dinv, b2, abuf, n, stats);
    finalize_kernel<<<1, 128, 0, stream>>>(stats, g2, be2, 1.0f / n, ss);

    // ---- layer 3 ----
    gemm_mfma<64, true><<<gemmGrid, 256, 0, stream>>>(abuf, wt3, hsb, n, ss, dinv);
    aggregate_kernel<64, false, false><<<aggGrid, 256, 0, stream>>>(hsb, csrsrc, rowptr, dinv, b3, out, n, nullptr);
}

// Round 8
// 480.881 us; speedup vs baseline: 1.1423x; 1.1423x over previous
//
#include <hip/hip_runtime.h>
#include <hip/hip_bf16.h>

// 3-layer GCN: bf16-MFMA GEMMs + CSR gather-reduce aggregation.
//   hs = bf16( dinv[row] * (act(A) @ W) )     (MFMA GEMM, act = BN+ReLU fused)
//   y[i] = dinv[i]*(hs[i] + sum_{e: s->i} hs[s]) + b  (fp32 acc, bf16 out)
// Aggregate ledger: time tracks gather-chain latency, not bytes (r5) nor
// instruction count (r7 regressed: 16-lane/16B). Best shape: 512 blocks,
// 32 lanes x uint2, x2 unroll (115us). This round: node-PAIR per group
// (i, i+n/2) -> 4 independent gathers in flight per group (2x MLP),
// same lanes/divergence/grid.

typedef __attribute__((ext_vector_type(8))) short short8;   // 8 bf16
typedef __attribute__((ext_vector_type(4))) float f32x4;    // 4 fp32 acc

__device__ inline unsigned short f2bf(float f) {  // round-to-nearest-even
    unsigned int u = __float_as_uint(f);
    return (unsigned short)((u + 0x7fff + ((u >> 16) & 1)) >> 16);
}
__device__ inline float bf2f_lo(unsigned int p) { return __uint_as_float(p << 16); }
__device__ inline float bf2f_hi(unsigned int p) { return __uint_as_float(p & 0xffff0000u); }

__device__ inline void bf4_acc(uint2 v, float* a) {
    a[0] += bf2f_lo(v.x); a[1] += bf2f_hi(v.x);
    a[2] += bf2f_lo(v.y); a[3] += bf2f_hi(v.y);
}

__global__ void count_deg_kernel(const int* __restrict__ dst, int E,
                                 int* __restrict__ rowptr1) {
    int e = blockIdx.x * blockDim.x + threadIdx.x;
    if (e < E) atomicAdd(rowptr1 + dst[e], 1);
}

__global__ void dinv_kernel(const int* __restrict__ rowptr, int n,
                            float* __restrict__ dinv) {
    int i = blockIdx.x * blockDim.x + threadIdx.x;
    if (i < n) dinv[i] = rsqrtf((float)(rowptr[i + 1] + 1));
}

// ---- 3-phase parallel inclusive scan over rowptr[0..total) ----
__global__ __launch_bounds__(256) void scanA_kernel(int* __restrict__ data,
                                                    int total,
                                                    int* __restrict__ bsum) {
    __shared__ int sh[256];
    const int t = threadIdx.x;
    const int base = blockIdx.x * 2048 + t * 8;
    int v[8];
    int run = 0;
#pragma unroll
    for (int j = 0; j < 8; ++j) {
        int idx = base + j;
        int x = (idx < total) ? data[idx] : 0;
        run += x;
        v[j] = run;
    }
    sh[t] = run;
    __syncthreads();
#pragma unroll
    for (int off = 1; off < 256; off <<= 1) {
        int add = (t >= off) ? sh[t - off] : 0;
        __syncthreads();
        sh[t] += add;
        __syncthreads();
    }
    int prev = (t > 0) ? sh[t - 1] : 0;
#pragma unroll
    for (int j = 0; j < 8; ++j) {
        int idx = base + j;
        if (idx < total) data[idx] = v[j] + prev;
    }
    if (t == 255) bsum[blockIdx.x] = sh[255];
}

__global__ void scanB_kernel(int* __restrict__ bsum, int nb) {
    __shared__ int sh[64];
    const int t = threadIdx.x;
    sh[t] = (t < nb) ? bsum[t] : 0;
    __syncthreads();
#pragma unroll
    for (int off = 1; off < 64; off <<= 1) {
        int add = (t >= off) ? sh[t - off] : 0;
        __syncthreads();
        sh[t] += add;
        __syncthreads();
    }
    if (t < nb) bsum[t] = sh[t];
}

__global__ __launch_bounds__(256) void scanC_kernel(int* __restrict__ data,
                                                    int total,
                                                    const int* __restrict__ bsum) {
    if (blockIdx.x == 0) return;
    const int off = bsum[blockIdx.x - 1];
    const int base = blockIdx.x * 2048 + threadIdx.x * 8;
#pragma unroll
    for (int j = 0; j < 8; ++j) {
        int idx = base + j;
        if (idx < total) data[idx] += off;
    }
}

__global__ void csr_build_kernel(const int* __restrict__ src,
                                 const int* __restrict__ dst, int E,
                                 int* __restrict__ rowptr,
                                 int* __restrict__ csr_src) {
    int e = blockIdx.x * blockDim.x + threadIdx.x;
    if (e < E) {
        int pos = atomicAdd(rowptr + dst[e], 1);
        csr_src[pos] = src[e];
    }
}

// Wt[nn][k] = bf16(W[k][nn]); K=128 fixed
__global__ void wt_bf16_kernel(const float* __restrict__ W, int NC,
                               unsigned short* __restrict__ Wt) {
    int idx = blockIdx.x * blockDim.x + threadIdx.x;
    if (idx < 128 * NC) {
        int k = idx / NC, nn = idx % NC;
        Wt[nn * 128 + k] = f2bf(W[idx]);
    }
}

// x fp32 -> bf16 (4 elems/thread)
__global__ void xcvt_kernel(const float* __restrict__ x,
                            unsigned short* __restrict__ xb, int total4) {
    int i = blockIdx.x * blockDim.x + threadIdx.x;
    if (i < total4) {
        float4 v = reinterpret_cast<const float4*>(x)[i];
        uint2 p;
        p.x = f2bf(v.x) | ((unsigned)f2bf(v.y) << 16);
        p.y = f2bf(v.z) | ((unsigned)f2bf(v.w) << 16);
        reinterpret_cast<uint2*>(xb)[i] = p;
    }
}

// C[n x NC] = bf16( dinv[row] * (act(A[n x 128]) @ W) ), A bf16, Wt bf16 (NCx128).
// act = identity or BN(scale,shift)+ReLU applied during A-staging.
// MFMA 16x16x32 bf16; layouts per m89/m120-verified mappings.
template <int NC, bool BN>
__global__ __launch_bounds__(256) void gemm_mfma(
    const unsigned short* __restrict__ A, const unsigned short* __restrict__ Wt,
    unsigned short* __restrict__ C, int n, const float* __restrict__ ss,
    const float* __restrict__ dinv) {
    __shared__ unsigned short Asd[64][136];   // +8 pad: 2-way bank (free)
    __shared__ unsigned short Bsd[NC][136];
    const int tid = threadIdx.x;
    const int wave = tid >> 6;
    const int lane = tid & 63;
    const int row0 = blockIdx.x * 64;

    // stage Bt (NC x 128)
    for (int idx = tid; idx < NC * 16; idx += 256) {
        int r = idx >> 4;
        int c = (idx & 15) * 8;
        uint4 v = *reinterpret_cast<const uint4*>(Wt + r * 128 + c);
        *reinterpret_cast<uint4*>(&Bsd[r][c]) = v;
    }
    // stage A rows (64 x 128) with optional BN+ReLU
    for (int idx = tid; idx < 64 * 16; idx += 256) {
        int r = idx >> 4;
        int c = (idx & 15) * 8;
        int grow = row0 + r;
        uint4 v = make_uint4(0u, 0u, 0u, 0u);
        if (grow < n)
            v = *reinterpret_cast<const uint4*>(A + (size_t)grow * 128 + c);
        if (BN) {
            unsigned int p[4] = {v.x, v.y, v.z, v.w};
#pragma unroll
            for (int h = 0; h < 4; ++h) {
                int f = c + h * 2;
                float lo = fmaxf(fmaf(bf2f_lo(p[h]), ss[f], ss[128 + f]), 0.f);
                float hi = fmaxf(fmaf(bf2f_hi(p[h]), ss[f + 1], ss[129 + f]), 0.f);
                p[h] = f2bf(lo) | ((unsigned)f2bf(hi) << 16);
            }
            v = make_uint4(p[0], p[1], p[2], p[3]);
        }
        *reinterpret_cast<uint4*>(&Asd[r][c]) = v;
    }
    __syncthreads();

    f32x4 acc[NC / 16];
#pragma unroll
    for (int t = 0; t < NC / 16; ++t) acc[t] = (f32x4)(0.f);

    const int l15 = lane & 15;
    const int quad = lane >> 4;
#pragma unroll
    for (int kb = 0; kb < 128; kb += 32) {
        short8 a = *reinterpret_cast<const short8*>(&Asd[wave * 16 + l15][kb + quad * 8]);
#pragma unroll
        for (int t = 0; t < NC / 16; ++t) {
            short8 b = *reinterpret_cast<const short8*>(&Bsd[t * 16 + l15][kb + quad * 8]);
            acc[t] = __builtin_amdgcn_mfma_f32_16x16x32_bf16(a, b, acc[t], 0, 0, 0);
        }
    }

    // epilogue: row = row0 + wave*16 + quad*4 + r ; col = t*16 + (lane&15)
    const int rbase = row0 + wave * 16 + quad * 4;
    float dv[4] = {0.f, 0.f, 0.f, 0.f};
    if (rbase < n) {  // dinv padded by +64 in ws
        float4 d4 = *reinterpret_cast<const float4*>(dinv + rbase);
        dv[0] = d4.x; dv[1] = d4.y; dv[2] = d4.z; dv[3] = d4.w;
    }
#pragma unroll
    for (int t = 0; t < NC / 16; ++t) {
        int col = t * 16 + l15;
#pragma unroll
        for (int r = 0; r < 4; ++r) {
            int row = rbase + r;
            if (row < n)
                C[(size_t)row * NC + col] = f2bf(acc[t][r] * dv[r]);
        }
    }
}

// Pairwise gather-reduce:
//   y[i] = dinv[i]*(hs[i] + sum_{e in row i} hs[csr_src[e]]) + bias
// Each LANES-lane group processes nodes (i, i+n/2) simultaneously; common-
// length main loop keeps 4 row-gathers in flight per group (x2 unroll x 2
// nodes). hs bf16 (uint2/lane); fp32 acc; out bf16 (OBF) or fp32.
// rowptr is POST-BUILD (rowptr[i] = end of row i; start = rowptr[i-1]).
template <int F, bool STATS, bool OBF>
__global__ __launch_bounds__(256) void aggregate_kernel(
    const unsigned short* __restrict__ hs, const int* __restrict__ csr_src,
    const int* __restrict__ rowptr, const float* __restrict__ dinv,
    const float* __restrict__ bias, void* __restrict__ outp, int n,
    float* __restrict__ stats) {
    const int LANES = F / 4;            // 32 for F=128, 16 for F=64
    const int GROUPS = 256 / LANES;
    const int lane = threadIdx.x % LANES;
    const int grp = threadIdx.x / LANES;
    const int fq = lane * 4;
    const float4 b4 = *reinterpret_cast<const float4*>(bias + fq);
    float s[4] = {}, sq[4] = {};

    const int half = n >> 1;
    const int G = gridDim.x * GROUPS;

    for (int i = blockIdx.x * GROUPS + grp; i < half; i += G) {
        const int iA = i, iB = i + half;
        int begA = (iA == 0) ? 0 : rowptr[iA - 1];
        int endA = rowptr[iA];
        int begB = rowptr[iB - 1];
        int endB = rowptr[iB];
        float aA[4] = {}, aB[4] = {};
        bf4_acc(*reinterpret_cast<const uint2*>(hs + (size_t)iA * F + fq), aA);
        bf4_acc(*reinterpret_cast<const uint2*>(hs + (size_t)iB * F + fq), aB);
        int eA = begA, eB = begB;
        int rem = min(endA - begA, endB - begB);
        for (; rem >= 2; rem -= 2) {
            int sA0 = csr_src[eA], sA1 = csr_src[eA + 1];
            int sB0 = csr_src[eB], sB1 = csr_src[eB + 1];
            uint2 vA0 = *reinterpret_cast<const uint2*>(hs + (size_t)sA0 * F + fq);
            uint2 vA1 = *reinterpret_cast<const uint2*>(hs + (size_t)sA1 * F + fq);
            uint2 vB0 = *reinterpret_cast<const uint2*>(hs + (size_t)sB0 * F + fq);
            uint2 vB1 = *reinterpret_cast<const uint2*>(hs + (size_t)sB1 * F + fq);
            bf4_acc(vA0, aA); bf4_acc(vA1, aA);
            bf4_acc(vB0, aB); bf4_acc(vB1, aB);
            eA += 2; eB += 2;
        }
        if (rem) {
            int sA0 = csr_src[eA], sB0 = csr_src[eB];
            uint2 vA0 = *reinterpret_cast<const uint2*>(hs + (size_t)sA0 * F + fq);
            uint2 vB0 = *reinterpret_cast<const uint2*>(hs + (size_t)sB0 * F + fq);
            bf4_acc(vA0, aA); bf4_acc(vB0, aB);
            ++eA; ++eB;
        }
        for (; eA + 1 < endA; eA += 2) {
            int s0 = csr_src[eA], s1 = csr_src[eA + 1];
            uint2 v0 = *reinterpret_cast<const uint2*>(hs + (size_t)s0 * F + fq);
            uint2 v1 = *reinterpret_cast<const uint2*>(hs + (size_t)s1 * F + fq);
            bf4_acc(v0, aA); bf4_acc(v1, aA);
        }
        if (eA < endA) {
            int s0 = csr_src[eA];
            bf4_acc(*reinterpret_cast<const uint2*>(hs + (size_t)s0 * F + fq), aA);
        }
        for (; eB + 1 < endB; eB += 2) {
            int s0 = csr_src[eB], s1 = csr_src[eB + 1];
            uint2 v0 = *reinterpret_cast<const uint2*>(hs + (size_t)s0 * F + fq);
            uint2 v1 = *reinterpret_cast<const uint2*>(hs + (size_t)s1 * F + fq);
            bf4_acc(v0, aB); bf4_acc(v1, aB);
        }
        if (eB < endB) {
            int s0 = csr_src[eB];
            bf4_acc(*reinterpret_cast<const uint2*>(hs + (size_t)s0 * F + fq), aB);
        }
        const float diA = dinv[iA], diB = dinv[iB];
        float yA[4], yB[4];
        yA[0] = fmaf(diA, aA[0], b4.x); yA[1] = fmaf(diA, aA[1], b4.y);
        yA[2] = fmaf(diA, aA[2], b4.z); yA[3] = fmaf(diA, aA[3], b4.w);
        yB[0] = fmaf(diB, aB[0], b4.x); yB[1] = fmaf(diB, aB[1], b4.y);
        yB[2] = fmaf(diB, aB[2], b4.z); yB[3] = fmaf(diB, aB[3], b4.w);
        if (OBF) {
            uint2 pA, pB;
            pA.x = f2bf(yA[0]) | ((unsigned)f2bf(yA[1]) << 16);
            pA.y = f2bf(yA[2]) | ((unsigned)f2bf(yA[3]) << 16);
            pB.x = f2bf(yB[0]) | ((unsigned)f2bf(yB[1]) << 16);
            pB.y = f2bf(yB[2]) | ((unsigned)f2bf(yB[3]) << 16);
            *reinterpret_cast<uint2*>((unsigned short*)outp + (size_t)iA * F + fq) = pA;
            *reinterpret_cast<uint2*>((unsigned short*)outp + (size_t)iB * F + fq) = pB;
        } else {
            *reinterpret_cast<float4*>((float*)outp + (size_t)iA * F + fq) =
                make_float4(yA[0], yA[1], yA[2], yA[3]);
            *reinterpret_cast<float4*>((float*)outp + (size_t)iB * F + fq) =
                make_float4(yB[0], yB[1], yB[2], yB[3]);
        }
        if (STATS) {
#pragma unroll
            for (int j = 0; j < 4; ++j) {
                s[j] += yA[j] + yB[j];
                sq[j] = fmaf(yA[j], yA[j], sq[j]);
                sq[j] = fmaf(yB[j], yB[j], sq[j]);
            }
        }
    }

    // odd-n leftover node (n-1), handled once by the first group
    if ((n & 1) && blockIdx.x == 0 && grp == 0) {
        const int i = n - 1;
        int beg = (i == 0) ? 0 : rowptr[i - 1];
        int end = rowptr[i];
        float a[4] = {};
        bf4_acc(*reinterpret_cast<const uint2*>(hs + (size_t)i * F + fq), a);
        for (int e = beg; e < end; ++e) {
            int s0 = csr_src[e];
            bf4_acc(*reinterpret_cast<const uint2*>(hs + (size_t)s0 * F + fq), a);
        }
        float di = dinv[i];
        float y[4];
        y[0] = fmaf(di, a[0], b4.x); y[1] = fmaf(di, a[1], b4.y);
        y[2] = fmaf(di, a[2], b4.z); y[3] = fmaf(di, a[3], b4.w);
        if (OBF) {
            uint2 p;
            p.x = f2bf(y[0]) | ((unsigned)f2bf(y[1]) << 16);
            p.y = f2bf(y[2]) | ((unsigned)f2bf(y[3]) << 16);
            *reinterpret_cast<uint2*>((unsigned short*)outp + (size_t)i * F + fq) = p;
        } else {
            *reinterpret_cast<float4*>((float*)outp + (size_t)i * F + fq) =
                make_float4(y[0], y[1], y[2], y[3]);
        }
        if (STATS) {
#pragma unroll
            for (int j = 0; j < 4; ++j) {
                s[j] += y[j];
                sq[j] = fmaf(y[j], y[j], sq[j]);
            }
        }
    }

    if (STATS) {  // F=128 shape: LANES=32, GROUPS=8
        __shared__ float sred[32][8];
#pragma unroll
        for (int q = 0; q < 8; ++q) {
            float v = (q < 4) ? s[q] : sq[q - 4];
            sred[lane][grp] = v;
            __syncthreads();
            if (grp == 0) {
                float t = 0.f;
#pragma unroll
                for (int g = 0; g < 8; ++g) t += sred[lane][g];
                int f = fq + (q & 3);
                atomicAdd(stats + ((q < 4) ? f : 128 + f), t);
            }
            __syncthreads();
        }
    }
}

// scale = g * rsqrt(var+eps); shift = be - mean*scale
__global__ void finalize_kernel(const float* __restrict__ stats,
                                const float* __restrict__ g,
                                const float* __restrict__ be, float invn,
                                float* __restrict__ ss) {
    int f = threadIdx.x;
    float mean = stats[f] * invn;
    float var = fmaf(-mean, mean, stats[128 + f] * invn);
    float sc = g[f] * rsqrtf(var + 1e-5f);
    ss[f] = sc;
    ss[128 + f] = fmaf(-mean, sc, be[f]);
}

extern "C" void kernel_launch(void* const* d_in, const int* in_sizes, int n_in,
                              void* d_out, int out_size, void* d_ws,
                              size_t ws_size, hipStream_t stream) {
    const float* x   = (const float*)d_in[0];
    const int*   ei  = (const int*)d_in[1];
    const float* W1  = (const float*)d_in[2];
    const float* b1  = (const float*)d_in[3];
    const float* g1  = (const float*)d_in[4];
    const float* be1 = (const float*)d_in[5];
    const float* W2  = (const float*)d_in[6];
    const float* b2  = (const float*)d_in[7];
    const float* g2  = (const float*)d_in[8];
    const float* be2 = (const float*)d_in[9];
    const float* W3  = (const float*)d_in[10];
    const float* b3  = (const float*)d_in[11];
    float* out = (float*)d_out;

    const int n = in_sizes[0] / 128;
    const int E = in_sizes[1] / 2;
    const int* src = ei;
    const int* dst = ei + E;

    float* wsf    = (float*)d_ws;
    float* dinv   = wsf;                         // n + 64 floats (padded)
    float* stats  = dinv + n + 64;               // 256
    float* ss     = stats + 256;                 // 256
    int*   rowptr = (int*)(ss + 256);            // n+1 ints
    int*   bsum   = rowptr + (n + 1);            // 64 ints
    int*   csrsrc = bsum + 64;                   // E ints
    unsigned short* wt1 = (unsigned short*)(csrsrc + E);      // 128*128
    unsigned short* wt2 = wt1 + 128 * 128;                    // 128*128
    unsigned short* wt3 = wt2 + 128 * 128;                    // 64*128
    unsigned short* abuf = wt3 + 64 * 128;                    // n*128 bf16
    unsigned short* hsb  = abuf + (size_t)n * 128;            // n*128 bf16

    const int total = n + 1;
    const int nb = (total + 2047) / 2048;

    // ---- CSR build + dinv + weight/x conversion ----
    hipMemsetAsync(rowptr, 0, (size_t)total * 4, stream);
    count_deg_kernel<<<(E + 255) / 256, 256, 0, stream>>>(dst, E, rowptr + 1);
    dinv_kernel<<<(n + 255) / 256, 256, 0, stream>>>(rowptr, n, dinv);
    scanA_kernel<<<nb, 256, 0, stream>>>(rowptr, total, bsum);
    scanB_kernel<<<1, 64, 0, stream>>>(bsum, nb);
    scanC_kernel<<<nb, 256, 0, stream>>>(rowptr, total, bsum);
    csr_build_kernel<<<(E + 255) / 256, 256, 0, stream>>>(src, dst, E, rowptr, csrsrc);
    wt_bf16_kernel<<<(128 * 128 + 255) / 256, 256, 0, stream>>>(W1, 128, wt1);
    wt_bf16_kernel<<<(128 * 128 + 255) / 256, 256, 0, stream>>>(W2, 128, wt2);
    wt_bf16_kernel<<<(128 * 64 + 255) / 256, 256, 0, stream>>>(W3, 64, wt3);
    xcvt_kernel<<<((n * 32) + 255) / 256, 256, 0, stream>>>(x, abuf, n * 32);

    const int gemmGrid = (n + 63) / 64;
    const int aggGrid = 512;  // proven best block count (r3/r4)

    // ---- layer 1 ----
    gemm_mfma<128, false><<<gemmGrid, 256, 0, stream>>>(abuf, wt1, hsb, n, nullptr, dinv);
    hipMemsetAsync(stats, 0, 256 * 4, stream);
    aggregate_kernel<128, true, true><<<aggGrid, 256, 0, stream>>>(hsb, csrsrc, rowptr, dinv, b1, abuf, n, stats);
    finalize_kernel<<<1, 128, 0, stream>>>(stats, g1, be1, 1.0f / n, ss);

    // ---- layer 2 ----
    gemm_mfma<128, true><<<gemmGrid, 256, 0, stream>>>(abuf, wt2, hsb, n, ss, dinv);
    hipMemsetAsync(stats, 0, 256 * 4, stream);
    aggregate_kernel<128, true, true><<<aggGrid, 256, 0, stream>>>(hsb, csrsrc, rowptr, dinv, b2, abuf, n, stats);
    finalize_kernel<<<1, 128, 0, stream>>>(stats, g2, be2, 1.0f / n, ss);

    // ---- layer 3 ----
    gemm_mfma<64, true><<<gemmGrid, 256, 0, stream>>>(abuf, wt3, hsb, n, ss, dinv);
    aggregate_kernel<64, false, false><<<aggGrid, 256, 0, stream>>>(hsb, csrsrc, rowptr, dinv, b3, out, n, nullptr);
}